// Round 10
// baseline (506.226 us; speedup 1.0000x reference)
//
#include <hip/hip_runtime.h>
#include <hip/hip_bf16.h>
#include <stdint.h>

// GroupedQAttention on MI355X.
// cast x->bf16, transpose-cast weights -> bf16 BT,
// GEMM1 (256^2 8-phase/2-tile, 16x16x32 MFMA, deep vmcnt(6) pipeline) -> qkvw,
// fused tiny-attention*w -> ow (bf16), GEMM2 (same) -> fp32 out.
// R3: row-major XCD chunk + plain stores. R5: supertile (kept).
// R7: vmcnt is PER-WAVE; staged reads need {VM-gate;BAR}. R9: 32x32 shape =
// 4-way LDS conflict (2.5e7) -> reverted to 16x16x32.
// R10: m201-faithful depth: 3 half-tiles in flight, VM6 gates at ph4/ph8 only,
// every stage->gate distance >=3 phases; NO sched_barrier pins except the
// mandatory one after lgkmcnt(0) (guide rule 18; m141: pinning regresses).

typedef __bf16 bf16;
typedef __bf16 bf16x8 __attribute__((ext_vector_type(8)));
typedef float f32x4 __attribute__((ext_vector_type(4)));

__device__ __forceinline__ void gload16(const bf16* g, bf16* l) {
  __builtin_amdgcn_global_load_lds(
      (const __attribute__((address_space(1))) void*)g,
      (__attribute__((address_space(3))) void*)l, 16, 0, 0);
}

#define BAR() __builtin_amdgcn_s_barrier()
#define SB() __builtin_amdgcn_sched_barrier(0)
#define LGKM0 asm volatile("s_waitcnt lgkmcnt(0)" ::: "memory")
#define VM6 asm volatile("s_waitcnt vmcnt(6)" ::: "memory")
#define VM0 asm volatile("s_waitcnt vmcnt(0)" ::: "memory")
#define PRIO1 __builtin_amdgcn_s_setprio(1)
#define PRIO0 __builtin_amdgcn_s_setprio(0)

// ---------- 256x256-tile GEMM: C[M][N] = A[M][1024] * BT[N][1024]^T ----------
// 512 threads = 8 waves (2Mx4N). BK=64; 16 K-tiles = 8 pairs (E=2j, O=2j+1).
// LDS 128KiB constant offsets: A0lo 0, A0hi 16384, A1lo 32768, A1hi 49152,
//   B0lo 65536, B0hi 81920, B1lo 98304, B1hi 114688 (half = 128 rows x 64).
// Swizzle involution on [128][64]bf16 halves: byte ^= ((byte>>7)&7)<<4.
// Phase = [reads][stage][gate?] BAR lgkm0+SB [16 MFMA] BAR.
// reads:  ph1 bn0<-B0nh0(4) | ph2 a0<-A0mq0(8), bn1<-B0nh1(4) | ph3 a1<-A0mq1(8)
//         ph5 bn0<-B1nh0(4) | ph6 a0<-A1mq0(8), bn1<-B1nh1(4) | ph7 a1<-A1mq1(8)
// MFMA:   ph1 (1,1)O-prev [j>0] | ph2 (0,0)E | ph3 (1,0)E | ph4 (0,1)E
//         ph5 (1,1)E | ph6 (0,0)O | ph7 (1,0)O | ph8 (0,1)O | post-loop (1,1)O
// stages: ph1 A1hi(t2j+1) | ph3 B0lo+B0hi(t2j+2) | ph4 A0lo | ph5 A0hi
//         ph7 B1lo(t2j+3) | ph8 B1hi+A1lo   [ph3..ph8 stages: j<7 only]
// gates:  ph4 VM6 (outstanding 14 -> drains B1-,A1-(prev)+A1hi: covers ph5-7
//         reads), ph8 VM6 (drains B0,A0: covers ph1'-3'). j==7: ph4 VM0.
// WAR: every stage follows victim's last-read LGKM0 + trailing BAR
//  (A1hi@1 <- rd ph7-; B0@3 <- rd ph2; A0lo@4 <- rd ph3; A0hi@5 <- rd ph3;
//   B1lo@7 <- rd ph6; B1hi,A1lo@8 <- rd ph6/ph7).
// Stage->gate distances: 3,5,4,3,5,4 slots (>=~750cyc, ~HBM latency).
#define READ_A8(dst, base, mq)                                                \
  {                                                                           \
    _Pragma("unroll") for (int i = 0; i < 4; ++i)                             \
        _Pragma("unroll") for (int kk = 0; kk < 2; ++kk)                      \
            dst[i][kk] = *(const bf16x8*)(lds + (base) + ahalf +              \
                                          ((mq)*64 + i * 16 + fr) * 128 +     \
                                          ((kk * 64 + fkb) ^ xo));            \
  }
#define READ_B4(dst, base, nh)                                                \
  {                                                                           \
    _Pragma("unroll") for (int j2 = 0; j2 < 2; ++j2)                          \
        _Pragma("unroll") for (int kk = 0; kk < 2; ++kk)                      \
            dst[j2][kk] = *(const bf16x8*)(lds + (base) + bhalf +             \
                                           (bro + (nh)*32 + j2 * 16 + fr) * 128 + \
                                           ((kk * 64 + fkb) ^ xo));           \
  }
#define MFMA_Q(arr, bv, mq, nh)                                               \
  {                                                                           \
    _Pragma("unroll") for (int i = 0; i < 4; ++i)                             \
        _Pragma("unroll") for (int j2 = 0; j2 < 2; ++j2) {                    \
      acc[(mq)*4 + i][(nh)*2 + j2] = __builtin_amdgcn_mfma_f32_16x16x32_bf16( \
          arr[i][0], bv[j2][0], acc[(mq)*4 + i][(nh)*2 + j2], 0, 0, 0);       \
      acc[(mq)*4 + i][(nh)*2 + j2] = __builtin_amdgcn_mfma_f32_16x16x32_bf16( \
          arr[i][1], bv[j2][1], acc[(mq)*4 + i][(nh)*2 + j2], 0, 0, 0);       \
    }                                                                         \
  }
#define STAGE(gsrc, lbase)                                                    \
  {                                                                           \
    gload16((gsrc), (bf16*)(lds + (lbase) + wv * 1024));                      \
    gload16((gsrc) + 64 * 1024, (bf16*)(lds + (lbase) + 8192 + wv * 1024));   \
  }

template <typename OutT>
__global__ __launch_bounds__(512, 2)
void gemm256(const bf16* __restrict__ A, const bf16* __restrict__ BT,
             OutT* __restrict__ C, int N, int super) {
  constexpr int K = 1024;
  __shared__ __align__(16) char smem[131072];
  char* lds = smem;

  const int tid = threadIdx.x;
  const int lane = tid & 63;
  const int wv = tid >> 6;
  const int wr = wv >> 2;  // 0..1
  const int wc = wv & 3;   // 0..3

  // XCD chunking + 8x4 supertiles (R5: FETCH 307->204MB)
  const int gx = gridDim.x;
  const int nwg = gx * gridDim.y;
  const int bid = blockIdx.y * gx + blockIdx.x;
  const int xcd = bid & 7;
  const int l = bid >> 3;
  long trow, tcol;
  if (super) {  // requires (nwg/8)/gx == 16 and gx%4==0
    const int s = l >> 5, i = l & 31;
    const int colS = gx >> 2;
    trow = xcd * 16 + (s / colS) * 8 + (i >> 2);
    tcol = (s % colS) * 4 + (i & 3);
  } else {
    const int swz = xcd * (nwg >> 3) + l;
    trow = swz / gx;
    tcol = swz % gx;
  }
  const long row0 = trow * 256;
  const long col0 = tcol * 256;

  // staging source (pre-swizzled so linear global_load_lds dest == swizzled layout)
  const int srow = tid >> 3;  // 0..63
  const int scol = (((tid & 7) * 16) ^ ((srow & 7) << 4)) >> 1;  // elements
  const bf16* gA = A + (row0 + srow) * K + scol;
  const bf16* gB = BT + (col0 + srow) * K + scol;

  // fragment read addressing
  const int fr = lane & 15;
  const int fkb = (lane >> 4) * 16;  // byte offset of k-slice
  const int xo = (fr & 7) << 4;
  const int bro = (wc & 1) * 64;
  const int ahalf = wr * 16384;
  const int bhalf = (wc >> 1) * 16384;

  bf16x8 a0[4][2], a1[4][2], bn0[2][2], bn1[2][2];
  f32x4 acc[8][4] = {};

  // prologue: t0 {A0lo,A0hi,B0lo,B0hi} + t1 {B1lo,B1hi,A1lo} = 14 loads.
  // VM6 drains t0's 8, keeps t1's 6 (= steady-state ph8-kept set); BAR.
  STAGE(gA, 0); STAGE(gA + 131072, 16384);
  STAGE(gB, 65536); STAGE(gB + 131072, 81920);
  STAGE(gB + 64, 98304); STAGE(gB + 131072 + 64, 114688);
  STAGE(gA + 64, 32768);
  VM6;
  BAR();

  const bf16* gAm = gA;
  const bf16* gBm = gB;
  for (int j = 0; j < 8; ++j) {
    const bool nl = (j < 7);
    // ph1: rd bn0<-B0nh0 | stage A1hi (t2j+1) | MFMA (1,1)O-prev
    READ_B4(bn0, 65536, 0);
    STAGE(gAm + 131072 + 64, 49152);
    BAR(); LGKM0; SB();
    if (j) { PRIO1; MFMA_Q(a1, bn1, 1, 1); PRIO0; }
    BAR();
    // ph2: rd a0<-A0mq0, bn1<-B0nh1 | MFMA (0,0)E
    READ_A8(a0, 0, 0);
    READ_B4(bn1, 65536, 1);
    BAR(); LGKM0; SB();
    PRIO1; MFMA_Q(a0, bn0, 0, 0); PRIO0;
    BAR();
    // ph3: rd a1<-A0mq1 | stage B0lo+B0hi (t2j+2) | MFMA (1,0)E
    READ_A8(a1, 0, 1);
    if (nl) { STAGE(gBm + 128, 65536); STAGE(gBm + 131072 + 128, 81920); }
    BAR(); LGKM0; SB();
    PRIO1; MFMA_Q(a1, bn0, 1, 0); PRIO0;
    BAR();
    // ph4: stage A0lo (t2j+2); gate VM6 | MFMA (0,1)E
    if (nl) {
      STAGE(gAm + 128, 0);
      VM6;
    } else {
      VM0;
    }
    BAR(); LGKM0; SB();
    PRIO1; MFMA_Q(a0, bn1, 0, 1); PRIO0;
    BAR();
    // ph5: rd bn0<-B1nh0 | stage A0hi | MFMA (1,1)E
    READ_B4(bn0, 98304, 0);
    if (nl) STAGE(gAm + 131072 + 128, 16384);
    BAR(); LGKM0; SB();
    PRIO1; MFMA_Q(a1, bn1, 1, 1); PRIO0;
    BAR();
    // ph6: rd a0<-A1mq0, bn1<-B1nh1 | MFMA (0,0)O
    READ_A8(a0, 32768, 0);
    READ_B4(bn1, 98304, 1);
    BAR(); LGKM0; SB();
    PRIO1; MFMA_Q(a0, bn0, 0, 0); PRIO0;
    BAR();
    // ph7: rd a1<-A1mq1 | stage B1lo (t2j+3) | MFMA (1,0)O
    READ_A8(a1, 32768, 1);
    if (nl) STAGE(gBm + 192, 98304);
    BAR(); LGKM0; SB();
    PRIO1; MFMA_Q(a1, bn0, 1, 0); PRIO0;
    BAR();
    // ph8: stage B1hi + A1lo (t2j+3); gate VM6 | MFMA (0,1)O
    if (nl) {
      STAGE(gBm + 131072 + 192, 114688);
      STAGE(gAm + 192, 32768);
      VM6;
    }
    BAR(); LGKM0; SB();
    PRIO1; MFMA_Q(a0, bn1, 0, 1); PRIO0;
    BAR();
    gAm += 128;
    gBm += 128;
  }
  // final O-quadrant (1,1) of tile 15 (regs a1@ph7, bn1@ph6 still live)
  PRIO1; MFMA_Q(a1, bn1, 1, 1); PRIO0;

  // epilogue: C/D layout col=lane&15, row=(lane>>4)*4+reg
  const int crow = (lane >> 4) * 4;
  const int ccol = lane & 15;
  const long rb = row0 + wr * 128;
  const long cb = col0 + wc * 64;
#pragma unroll
  for (int m = 0; m < 8; ++m)
#pragma unroll
    for (int n = 0; n < 4; ++n)
#pragma unroll
      for (int i = 0; i < 4; ++i)
        C[(rb + m * 16 + crow + i) * (long)N + cb + n * 16 + ccol] =
            (OutT)acc[m][n][i];
}

// ---------------- fused tiny attention ----------------
__device__ __forceinline__ void load16f(const bf16* p, float* f) {
  const uint4* u = (const uint4*)p;
  uint4 a = u[0], b = u[1];
  uint32_t w[8] = {a.x, a.y, a.z, a.w, b.x, b.y, b.z, b.w};
#pragma unroll
  for (int j = 0; j < 8; ++j) {
    f[2 * j] = __uint_as_float(w[j] << 16);
    f[2 * j + 1] = __uint_as_float(w[j] & 0xffff0000u);
  }
}

// block = (s_hi, g, bz); 256 threads = 16 s_lo x 16 h1
__global__ __launch_bounds__(256)
void attn_fuse(const bf16* __restrict__ qkvw, bf16* __restrict__ ow,
               int b0, long bstride) {
  __shared__ bf16 data[16 * 1024];
  const int s_hi = blockIdx.x;
  const int g = blockIdx.y;
  const int bz = blockIdx.z;
  const int b = b0 + bz;
  const bf16* base = qkvw + (long)bz * bstride;
  const int tid = threadIdx.x;

#pragma unroll
  for (int i = 0; i < 8; ++i) {
    int c = tid + i * 256;
    int h = c >> 7;
    int col = (c & 127) * 8;
    *(uint4*)&data[h * 1024 + col] =
        *(const uint4*)(base + (long)(h * 256 + s_hi) * 4096 + g * 1024 + col);
  }
  __syncthreads();

  const int s_lo = tid >> 4;
  const int h1 = tid & 15;
  const int off = s_lo * 16;

  float q[16], p[16], o[16];
  load16f(&data[h1 * 1024 + off], q);

  float mx = -1e30f;
#pragma unroll
  for (int h2 = 0; h2 < 16; ++h2) {
    float kf[16];
    load16f(&data[h2 * 1024 + 256 + off], kf);
    float s = 0.f;
#pragma unroll
    for (int d = 0; d < 16; ++d) s += q[d] * kf[d];
    s *= 0.25f;  // HD^-0.5, HD=16
    p[h2] = s;
    mx = fmaxf(mx, s);
  }
  float sum = 0.f;
#pragma unroll
  for (int h2 = 0; h2 < 16; ++h2) {
    float e = __expf(p[h2] - mx);
    p[h2] = e;
    sum += e;
  }
  const float inv = 1.f / sum;
#pragma unroll
  for (int d = 0; d < 16; ++d) o[d] = 0.f;
#pragma unroll
  for (int h2 = 0; h2 < 16; ++h2) {
    float vf[16];
    load16f(&data[h2 * 1024 + 512 + off], vf);
    const float av = p[h2] * inv;
#pragma unroll
    for (int d = 0; d < 16; ++d) o[d] += av * vf[d];
  }
  float wf[16];
  load16f(&data[h1 * 1024 + 768 + off], wf);

  const int bp = g * 8 + b;  // concat index along axis 0
  const long R = (long)(bp >> 2) * 4096 + (bp & 3) * 1024 + h1 * 64 + (s_hi >> 2);
  const int cbo = (s_hi & 3) * 256 + off;
  union { uint4 u[2]; bf16 hh[16]; } st;
#pragma unroll
  for (int d = 0; d < 16; ++d) st.hh[d] = (bf16)(o[d] * wf[d]);
  uint4* dst = (uint4*)&ow[R * 1024 + cbo];
  dst[0] = st.u[0];
  dst[1] = st.u[1];
}

// ---------------- casts ----------------
__global__ __launch_bounds__(256)
void cast_x_kernel(const float* __restrict__ in, bf16* __restrict__ out, long n4) {
  long i = (long)blockIdx.x * 256 + threadIdx.x;
  if (i >= n4) return;
  float4 v = ((const float4*)in)[i];
  union { uint2 d; bf16 h[4]; } r;
  r.h[0] = (bf16)v.x; r.h[1] = (bf16)v.y; r.h[2] = (bf16)v.z; r.h[3] = (bf16)v.w;
  ((uint2*)out)[i] = r.d;
}

// out[C][R] = bf16(in[R][C])  (transpose-cast, 64x64 tiles)
__global__ __launch_bounds__(256)
void tcast_kernel(const float* __restrict__ in, bf16* __restrict__ out, int R, int C) {
  __shared__ float t[64][65];
  const int c0 = blockIdx.x * 64, r0 = blockIdx.y * 64;
  const int lr = threadIdx.x >> 6;
  const int lc = threadIdx.x & 63;
#pragma unroll
  for (int i = 0; i < 16; ++i)
    t[lr + i * 4][lc] = in[(long)(r0 + lr + i * 4) * C + c0 + lc];
  __syncthreads();
#pragma unroll
  for (int i = 0; i < 16; ++i) {
    int oc = lr + i * 4;
    out[(long)(c0 + oc) * R + r0 + lc] = (bf16)t[lc][oc];
  }
}

// ---------------- launch ----------------
extern "C" void kernel_launch(void* const* d_in, const int* in_sizes, int n_in,
                              void* d_out, int out_size, void* d_ws, size_t ws_size,
                              hipStream_t stream) {
  const float* x = (const float*)d_in[0];
  const float* w_qkvw = (const float*)d_in[1];
  const float* w_out = (const float*)d_in[2];
  float* out = (float*)d_out;

  char* ws = (char*)d_ws;
  size_t off = 0;
  bf16* x_bf = (bf16*)(ws + off); off += (size_t)32768 * 1024 * 2;
  bf16* bt1  = (bf16*)(ws + off); off += (size_t)4096 * 1024 * 2;
  bf16* bt2  = (bf16*)(ws + off); off += (size_t)1024 * 1024 * 2;
  bf16* owb  = (bf16*)(ws + off); off += (size_t)32768 * 1024 * 2;
  bf16* qk   = (bf16*)(ws + off);
  const size_t rem = ws_size > off ? ws_size - off : 0;
  const size_t full_need = (size_t)32768 * 4096 * 2;

  cast_x_kernel<<<32768, 256, 0, stream>>>(x, x_bf, (long)8388608);
  tcast_kernel<<<dim3(64, 16), 256, 0, stream>>>(w_qkvw, bt1, 1024, 4096);
  tcast_kernel<<<dim3(16, 16), 256, 0, stream>>>(w_out, bt2, 1024, 1024);

  if (rem >= full_need) {
    gemm256<bf16><<<dim3(16, 128), 512, 0, stream>>>(x_bf, bt1, qk, 4096, 1);
    attn_fuse<<<dim3(256, 4, 8), 256, 0, stream>>>(qk, owb, 0, (long)4096 * 4096);
  } else {
    for (int b = 0; b < 8; ++b) {
      gemm256<bf16><<<dim3(16, 16), 512, 0, stream>>>(
          x_bf + (size_t)b * 4096 * 1024, bt1, qk, 4096, 0);
      attn_fuse<<<dim3(256, 4, 1), 256, 0, stream>>>(qk, owb, b, 0);
    }
  }
  gemm256<float><<<dim3(4, 128), 512, 0, stream>>>(owb, bt2, out, 1024, 1);
}

// Round 11
// 452.149 us; speedup vs baseline: 1.1196x; 1.1196x over previous
//
#include <hip/hip_runtime.h>
#include <hip/hip_bf16.h>
#include <stdint.h>

// GroupedQAttention on MI355X.
// cast x->bf16, transpose-cast weights -> bf16 BT,
// GEMM1 (256^2, 8-phase/2-tile, ONE barrier/phase + counted lgkm) -> qkvw,
// fused tiny-attention*w -> ow (bf16), GEMM2 (same) -> fp32 out.
// R3: row-major XCD chunk + plain stores. R5: supertile (kept).
// R7: vmcnt is PER-WAVE; staged reads need {VM-gate;BAR}. R9: 32x32 MFMA =
// 4-way LDS conflict -> 16x16x32. R10: rotated ring spilled past the hard
// 128-VGPR cap (8 waves => 2/SIMD => <=128) -> reverted.
// R11: single barrier per phase (8 vs 16 per tile-pair) + counted lgkmcnt
// so next-phase ds_reads drain under the current MFMA cluster. Stage slots,
// gates, regions = R8 verbatim. WAR proof: stage_p issues post-BAR_p, which
// is after every wave's reads of the victim region (drained by its lgkm at
// p-1) -- one barrier suffices. RAW: {VM4@ph4/ph8 ; BAR@next} unchanged.

typedef __bf16 bf16;
typedef __bf16 bf16x8 __attribute__((ext_vector_type(8)));
typedef float f32x4 __attribute__((ext_vector_type(4)));

__device__ __forceinline__ void gload16(const bf16* g, bf16* l) {
  __builtin_amdgcn_global_load_lds(
      (const __attribute__((address_space(1))) void*)g,
      (__attribute__((address_space(3))) void*)l, 16, 0, 0);
}

#define BAR() __builtin_amdgcn_s_barrier()
#define SB() __builtin_amdgcn_sched_barrier(0)
#define LGKM8 asm volatile("s_waitcnt lgkmcnt(8)" ::: "memory")
#define LGKM4 asm volatile("s_waitcnt lgkmcnt(4)" ::: "memory")
#define LGKM0 asm volatile("s_waitcnt lgkmcnt(0)" ::: "memory")
#define VM4 asm volatile("s_waitcnt vmcnt(4)" ::: "memory")
#define VM0 asm volatile("s_waitcnt vmcnt(0)" ::: "memory")
#define PRIO1 __builtin_amdgcn_s_setprio(1)
#define PRIO0 __builtin_amdgcn_s_setprio(0)

// ---------- 256x256-tile GEMM: C[M][N] = A[M][1024] * BT[N][1024]^T ----------
// 512 threads = 8 waves (2Mx4N). BK=64; 16 K-tiles = 8 pairs (E=2j, O=2j+1).
// LDS 128KiB constant offsets: A0lo 0, A0hi 16384, A1lo 32768, A1hi 49152,
//   B0lo 65536, B0hi 81920, B1lo 98304, B1hi 114688 (A0/B0=E, A1/B1=O).
// Swizzle involution on [128][64]bf16 halves: byte ^= ((byte>>7)&7)<<4.
// Phase p = BAR ; [reads_p][stage_p][gate_p?] ; lgkm(K) ; SB ; 16 MFMA.
//  ph1: rd bn0<-B0nh0(4), a0<-A0mq0(8), a1<-A0mq1(8) | st B1lo(t2j+1) |
//       lgkm(8) (a1 may stay outstanding) | MFMA(0,0)E
//  ph2: rd bn1<-B0nh1(4) | st B1hi | lgkm(4) | MFMA(1,0)E
//  ph3: st A0lo(t2j+2) | lgkm(0) | MFMA(1,1)E
//  ph4: st A0hi ; VM4 | MFMA(0,1)E
//  ph5-8: mirror on A1/B1, staging B0lo/B0hi(t2j+2), A1lo/A1hi(t2j+3);
//         ph8 gate VM4. j==7: no stages, ph4 VM0, no ph8 gate.
// Gate arithmetic (gloads): @ph4: leftover A1(4) + B1(4) + A0(4) = 12;
//  VM4 leaves A0's 4 -> drains A1,B1 (= ph5-7 reads). @ph8: leftover A0(4)
//  + B0(4) + A1(4) = 12; VM4 leaves A1 -> drains A0,B0 (= ph1'-3' reads).
// WAR per stage: B1@ph1 (last rd bn1@ph6', drained lgkm0@ph7' < BAR@ph8' <
//  BAR@ph1); A0@ph3 (rd ph1, drained lgkm@ph1/2 < BAR@ph3); B0@ph5 (rd
//  ph1/2, drained lgkm0@ph3 < BAR@ph5); A1@ph7 (rd ph5/6 < BAR@ph7).
#define READ_A8(dst, base, mq)                                                \
  {                                                                           \
    _Pragma("unroll") for (int i = 0; i < 4; ++i)                             \
        _Pragma("unroll") for (int kk = 0; kk < 2; ++kk)                      \
            dst[i][kk] = *(const bf16x8*)(lds + (base) + ahalf +              \
                                          ((mq)*64 + i * 16 + fr) * 128 +     \
                                          ((kk * 64 + fkb) ^ xo));            \
  }
#define READ_B4(dst, base, nh)                                                \
  {                                                                           \
    _Pragma("unroll") for (int j2 = 0; j2 < 2; ++j2)                          \
        _Pragma("unroll") for (int kk = 0; kk < 2; ++kk)                      \
            dst[j2][kk] = *(const bf16x8*)(lds + (base) + bhalf +             \
                                           (bro + (nh)*32 + j2 * 16 + fr) * 128 + \
                                           ((kk * 64 + fkb) ^ xo));           \
  }
#define MFMA_Q(arr, bv, mq, nh)                                               \
  {                                                                           \
    _Pragma("unroll") for (int i = 0; i < 4; ++i)                             \
        _Pragma("unroll") for (int j2 = 0; j2 < 2; ++j2) {                    \
      acc[(mq)*4 + i][(nh)*2 + j2] = __builtin_amdgcn_mfma_f32_16x16x32_bf16( \
          arr[i][0], bv[j2][0], acc[(mq)*4 + i][(nh)*2 + j2], 0, 0, 0);       \
      acc[(mq)*4 + i][(nh)*2 + j2] = __builtin_amdgcn_mfma_f32_16x16x32_bf16( \
          arr[i][1], bv[j2][1], acc[(mq)*4 + i][(nh)*2 + j2], 0, 0, 0);       \
    }                                                                         \
  }
#define STAGE(gsrc, lbase)                                                    \
  {                                                                           \
    gload16((gsrc), (bf16*)(lds + (lbase) + wv * 1024));                      \
    gload16((gsrc) + 64 * 1024, (bf16*)(lds + (lbase) + 8192 + wv * 1024));   \
  }

template <typename OutT>
__global__ __launch_bounds__(512, 2)
void gemm256(const bf16* __restrict__ A, const bf16* __restrict__ BT,
             OutT* __restrict__ C, int N, int super) {
  constexpr int K = 1024;
  __shared__ __align__(16) char smem[131072];
  char* lds = smem;

  const int tid = threadIdx.x;
  const int lane = tid & 63;
  const int wv = tid >> 6;
  const int wr = wv >> 2;  // 0..1
  const int wc = wv & 3;   // 0..3

  // XCD chunking + 8x4 supertiles (R5: FETCH 307->204MB)
  const int gx = gridDim.x;
  const int nwg = gx * gridDim.y;
  const int bid = blockIdx.y * gx + blockIdx.x;
  const int xcd = bid & 7;
  const int l = bid >> 3;
  long trow, tcol;
  if (super) {  // requires (nwg/8)/gx == 16 and gx%4==0
    const int s = l >> 5, i = l & 31;
    const int colS = gx >> 2;
    trow = xcd * 16 + (s / colS) * 8 + (i >> 2);
    tcol = (s % colS) * 4 + (i & 3);
  } else {
    const int swz = xcd * (nwg >> 3) + l;
    trow = swz / gx;
    tcol = swz % gx;
  }
  const long row0 = trow * 256;
  const long col0 = tcol * 256;

  // staging source (pre-swizzled so linear global_load_lds dest == swizzled layout)
  const int srow = tid >> 3;  // 0..63
  const int scol = (((tid & 7) * 16) ^ ((srow & 7) << 4)) >> 1;  // elements
  const bf16* gA = A + (row0 + srow) * K + scol;
  const bf16* gB = BT + (col0 + srow) * K + scol;

  // fragment read addressing
  const int fr = lane & 15;
  const int fkb = (lane >> 4) * 16;  // byte offset of k-slice
  const int xo = (fr & 7) << 4;
  const int bro = (wc & 1) * 64;
  const int ahalf = wr * 16384;
  const int bhalf = (wc >> 1) * 16384;

  bf16x8 a0[4][2], a1[4][2], bn0[2][2], bn1[2][2];
  f32x4 acc[8][4] = {};

  // prologue: A0(t0), B0(t0), A1(t1) = 12 gloads; VM4 leaves A1's 4 in
  // flight, drains t0's 8; first loop BAR makes them globally visible.
  STAGE(gA, 0); STAGE(gA + 131072, 16384);
  STAGE(gB, 65536); STAGE(gB + 131072, 81920);
  STAGE(gA + 64, 32768); STAGE(gA + 131072 + 64, 49152);
  VM4;

  const bf16* gAm = gA;
  const bf16* gBm = gB;
  for (int j = 0; j < 8; ++j) {
    const bool nl = (j < 7);
    // ph1
    BAR();
    READ_B4(bn0, 65536, 0);
    READ_A8(a0, 0, 0);
    READ_A8(a1, 0, 1);
    STAGE(gBm + 64, 98304);
    LGKM8; SB();
    PRIO1; MFMA_Q(a0, bn0, 0, 0); PRIO0;
    // ph2
    BAR();
    READ_B4(bn1, 65536, 1);
    STAGE(gBm + 131072 + 64, 114688);
    LGKM4; SB();
    PRIO1; MFMA_Q(a1, bn0, 1, 0); PRIO0;
    // ph3
    BAR();
    if (nl) STAGE(gAm + 128, 0);
    LGKM0; SB();
    PRIO1; MFMA_Q(a1, bn1, 1, 1); PRIO0;
    // ph4: gate (covers A1,B1 for ph5-7; reads are post-BAR@ph5)
    BAR();
    if (nl) {
      STAGE(gAm + 131072 + 128, 16384);
      VM4;
    } else {
      VM0;
    }
    SB();
    PRIO1; MFMA_Q(a0, bn1, 0, 1); PRIO0;
    // ph5
    BAR();
    READ_B4(bn0, 98304, 0);
    READ_A8(a0, 32768, 0);
    READ_A8(a1, 32768, 1);
    if (nl) STAGE(gBm + 128, 65536);
    LGKM8; SB();
    PRIO1; MFMA_Q(a0, bn0, 0, 0); PRIO0;
    // ph6
    BAR();
    READ_B4(bn1, 98304, 1);
    if (nl) STAGE(gBm + 131072 + 128, 81920);
    LGKM4; SB();
    PRIO1; MFMA_Q(a1, bn0, 1, 0); PRIO0;
    // ph7
    BAR();
    if (nl) STAGE(gAm + 192, 32768);
    LGKM0; SB();
    PRIO1; MFMA_Q(a1, bn1, 1, 1); PRIO0;
    // ph8: gate (covers A0,B0 for next pair's ph1-3)
    BAR();
    if (nl) {
      STAGE(gAm + 131072 + 192, 49152);
      VM4;
    }
    SB();
    PRIO1; MFMA_Q(a0, bn1, 0, 1); PRIO0;
    gAm += 128;
    gBm += 128;
  }

  // epilogue: C/D layout col=lane&15, row=(lane>>4)*4+reg
  const int crow = (lane >> 4) * 4;
  const int ccol = lane & 15;
  const long rb = row0 + wr * 128;
  const long cb = col0 + wc * 64;
#pragma unroll
  for (int m = 0; m < 8; ++m)
#pragma unroll
    for (int n = 0; n < 4; ++n)
#pragma unroll
      for (int i = 0; i < 4; ++i)
        C[(rb + m * 16 + crow + i) * (long)N + cb + n * 16 + ccol] =
            (OutT)acc[m][n][i];
}

// ---------------- fused tiny attention ----------------
__device__ __forceinline__ void load16f(const bf16* p, float* f) {
  const uint4* u = (const uint4*)p;
  uint4 a = u[0], b = u[1];
  uint32_t w[8] = {a.x, a.y, a.z, a.w, b.x, b.y, b.z, b.w};
#pragma unroll
  for (int j = 0; j < 8; ++j) {
    f[2 * j] = __uint_as_float(w[j] << 16);
    f[2 * j + 1] = __uint_as_float(w[j] & 0xffff0000u);
  }
}

// block = (s_hi, g, bz); 256 threads = 16 s_lo x 16 h1
__global__ __launch_bounds__(256)
void attn_fuse(const bf16* __restrict__ qkvw, bf16* __restrict__ ow,
               int b0, long bstride) {
  __shared__ bf16 data[16 * 1024];
  const int s_hi = blockIdx.x;
  const int g = blockIdx.y;
  const int bz = blockIdx.z;
  const int b = b0 + bz;
  const bf16* base = qkvw + (long)bz * bstride;
  const int tid = threadIdx.x;

#pragma unroll
  for (int i = 0; i < 8; ++i) {
    int c = tid + i * 256;
    int h = c >> 7;
    int col = (c & 127) * 8;
    *(uint4*)&data[h * 1024 + col] =
        *(const uint4*)(base + (long)(h * 256 + s_hi) * 4096 + g * 1024 + col);
  }
  __syncthreads();

  const int s_lo = tid >> 4;
  const int h1 = tid & 15;
  const int off = s_lo * 16;

  float q[16], p[16], o[16];
  load16f(&data[h1 * 1024 + off], q);

  float mx = -1e30f;
#pragma unroll
  for (int h2 = 0; h2 < 16; ++h2) {
    float kf[16];
    load16f(&data[h2 * 1024 + 256 + off], kf);
    float s = 0.f;
#pragma unroll
    for (int d = 0; d < 16; ++d) s += q[d] * kf[d];
    s *= 0.25f;  // HD^-0.5, HD=16
    p[h2] = s;
    mx = fmaxf(mx, s);
  }
  float sum = 0.f;
#pragma unroll
  for (int h2 = 0; h2 < 16; ++h2) {
    float e = __expf(p[h2] - mx);
    p[h2] = e;
    sum += e;
  }
  const float inv = 1.f / sum;
#pragma unroll
  for (int d = 0; d < 16; ++d) o[d] = 0.f;
#pragma unroll
  for (int h2 = 0; h2 < 16; ++h2) {
    float vf[16];
    load16f(&data[h2 * 1024 + 512 + off], vf);
    const float av = p[h2] * inv;
#pragma unroll
    for (int d = 0; d < 16; ++d) o[d] += av * vf[d];
  }
  float wf[16];
  load16f(&data[h1 * 1024 + 768 + off], wf);

  const int bp = g * 8 + b;  // concat index along axis 0
  const long R = (long)(bp >> 2) * 4096 + (bp & 3) * 1024 + h1 * 64 + (s_hi >> 2);
  const int cbo = (s_hi & 3) * 256 + off;
  union { uint4 u[2]; bf16 hh[16]; } st;
#pragma unroll
  for (int d = 0; d < 16; ++d) st.hh[d] = (bf16)(o[d] * wf[d]);
  uint4* dst = (uint4*)&ow[R * 1024 + cbo];
  dst[0] = st.u[0];
  dst[1] = st.u[1];
}

// ---------------- casts ----------------
__global__ __launch_bounds__(256)
void cast_x_kernel(const float* __restrict__ in, bf16* __restrict__ out, long n4) {
  long i = (long)blockIdx.x * 256 + threadIdx.x;
  if (i >= n4) return;
  float4 v = ((const float4*)in)[i];
  union { uint2 d; bf16 h[4]; } r;
  r.h[0] = (bf16)v.x; r.h[1] = (bf16)v.y; r.h[2] = (bf16)v.z; r.h[3] = (bf16)v.w;
  ((uint2*)out)[i] = r.d;
}

// out[C][R] = bf16(in[R][C])  (transpose-cast, 64x64 tiles)
__global__ __launch_bounds__(256)
void tcast_kernel(const float* __restrict__ in, bf16* __restrict__ out, int R, int C) {
  __shared__ float t[64][65];
  const int c0 = blockIdx.x * 64, r0 = blockIdx.y * 64;
  const int lr = threadIdx.x >> 6;
  const int lc = threadIdx.x & 63;
#pragma unroll
  for (int i = 0; i < 16; ++i)
    t[lr + i * 4][lc] = in[(long)(r0 + lr + i * 4) * C + c0 + lc];
  __syncthreads();
#pragma unroll
  for (int i = 0; i < 16; ++i) {
    int oc = lr + i * 4;
    out[(long)(c0 + oc) * R + r0 + lc] = (bf16)t[lc][oc];
  }
}

// ---------------- launch ----------------
extern "C" void kernel_launch(void* const* d_in, const int* in_sizes, int n_in,
                              void* d_out, int out_size, void* d_ws, size_t ws_size,
                              hipStream_t stream) {
  const float* x = (const float*)d_in[0];
  const float* w_qkvw = (const float*)d_in[1];
  const float* w_out = (const float*)d_in[2];
  float* out = (float*)d_out;

  char* ws = (char*)d_ws;
  size_t off = 0;
  bf16* x_bf = (bf16*)(ws + off); off += (size_t)32768 * 1024 * 2;
  bf16* bt1  = (bf16*)(ws + off); off += (size_t)4096 * 1024 * 2;
  bf16* bt2  = (bf16*)(ws + off); off += (size_t)1024 * 1024 * 2;
  bf16* owb  = (bf16*)(ws + off); off += (size_t)32768 * 1024 * 2;
  bf16* qk   = (bf16*)(ws + off);
  const size_t rem = ws_size > off ? ws_size - off : 0;
  const size_t full_need = (size_t)32768 * 4096 * 2;

  cast_x_kernel<<<32768, 256, 0, stream>>>(x, x_bf, (long)8388608);
  tcast_kernel<<<dim3(64, 16), 256, 0, stream>>>(w_qkvw, bt1, 1024, 4096);
  tcast_kernel<<<dim3(16, 16), 256, 0, stream>>>(w_out, bt2, 1024, 1024);

  if (rem >= full_need) {
    gemm256<bf16><<<dim3(16, 128), 512, 0, stream>>>(x_bf, bt1, qk, 4096, 1);
    attn_fuse<<<dim3(256, 4, 8), 256, 0, stream>>>(qk, owb, 0, (long)4096 * 4096);
  } else {
    for (int b = 0; b < 8; ++b) {
      gemm256<bf16><<<dim3(16, 16), 512, 0, stream>>>(
          x_bf + (size_t)b * 4096 * 1024, bt1, qk, 4096, 0);
      attn_fuse<<<dim3(256, 4, 1), 256, 0, stream>>>(qk, owb, b, 0);
    }
  }
  gemm256<float><<<dim3(4, 128), 512, 0, stream>>>(owb, bt2, out, 1024, 1);
}